// Round 5
// baseline (9432.458 us; speedup 1.0000x reference)
//
#include <hip/hip_runtime.h>
#include <hip/hip_fp16.h>

// GRUPK R5: MFMA recurrence. Weights live in AGPR/VGPR as MFMA B-fragments
// (MFMA reads AGPR operands natively -> no v_accvgpr_read shuttle, which is
// what killed the VALU-dot design at 208us/dispatch: VGPR=84 + ~86 AGPR with
// per-use shuttle, VALUBusy 55%).
//
// recur (per layer, per 128-step chunk): 16 blocks x 512 thr (8 waves).
//   block = 16 batches. wave w owns gate tiles {2w,2w+1,16+2w,17+2w,32+2w,33+2w}
//   so each lane holds full (r,z,n) triples in its C-frags; h' computed per-lane,
//   h state register-resident across steps. LDS holds h in MFMA-A frag layout
//   (contiguous conflict-free b128 reads). W frags preloaded: 48 half8 = 192 regs.
// phaseB0: xg0t[s][g][b] = x,meta @ Wih0^T + bih0 (K=8, memory-bound).
// phaseB1: xg1t[s][g][b] = h0 @ Wih1^T + bih1, LDS-free MFMA GEMM reading
//   h0 directly in frag layout (houtfrag) written by recur L0.
// xg0t/xg1t alias one buffer (disjoint lifetimes).
//
// ws layout (bytes):
//   0         Wfrag0   [8 kt][48 nt][64 lane][8] f16   393216
//   393216    Wfrag1   393216
//   786432    Wi1frag  393216
//   1179648   hstateF0 f32 [16 blk][8 w][64][8]        262144
//   1441792   hstateF1 262144
//   1703936   houtfrag f16 [128 s][16 btile][8 kt][512] 16777216
//   18481152  xgt      f16 [128 s][768 g][256 b]        50331648
//   total 68812800

#define CHUNK 128
#define NCHUNK 8

typedef _Float16 half8 __attribute__((ext_vector_type(8)));
typedef _Float16 half4_t __attribute__((ext_vector_type(4)));
typedef float f32x4 __attribute__((ext_vector_type(4)));

__device__ __forceinline__ float sigf(float v) {
    return 1.f / (1.f + __expf(-v));
}
__device__ __forceinline__ float tanh_(float v) {
    float a = fabsf(v);
    float e = __expf(-2.f * a);
    float r = (1.f - e) / (1.f + e);
    return copysignf(r, v);
}

// ---------- prep: W -> MFMA B-fragment layout [kt][nt][lane][8] f16 ----------
__global__ __launch_bounds__(256) void prep_kernel(
    const float* __restrict__ Whh0, const float* __restrict__ Whh1,
    const float* __restrict__ Wih1,
    _Float16* __restrict__ Wfrag0, _Float16* __restrict__ Wfrag1,
    _Float16* __restrict__ Wi1frag) {
    int tid = blockIdx.x * 256 + threadIdx.x;     // 3 * 24576 = 73728
    int mat = tid / 24576;
    int r   = tid % 24576;                        // = (kt*48 + nt)*64 + lane
    int kt   = r / 3072;
    int rem  = r % 3072;
    int nt   = rem >> 6;
    int lane = rem & 63;
    int n = nt * 16 + (lane & 15);
    int k = kt * 32 + (lane >> 4) * 8;
    const float* src = (mat == 0 ? Whh0 : (mat == 1 ? Whh1 : Wih1)) + n * 256 + k;
    _Float16* dst = (mat == 0 ? Wfrag0 : (mat == 1 ? Wfrag1 : Wi1frag)) + (size_t)r * 8;
#pragma unroll
    for (int j = 0; j < 8; j++) dst[j] = (_Float16)src[j];
}

// ---------- phaseB0: xg0t[s][g][b] = [x|meta] @ Wih0^T + bih0 ----------
__global__ __launch_bounds__(128) void phaseB0_kernel(
    const float* __restrict__ x, const float* __restrict__ meta,
    const float* __restrict__ Wih0, const float* __restrict__ bih0,
    _Float16* __restrict__ xgt, int chunk) {
    __shared__ float Wg[768 * 8 + 768];   // rows + bias
    int tid = threadIdx.x;
    for (int i = tid; i < 6912; i += 128)
        Wg[i] = (i < 6144) ? Wih0[i] : bih0[i - 6144];
    __syncthreads();
    int s_local = blockIdx.x >> 2, bg = blockIdx.x & 3;
    int wv = tid >> 6, lane = tid & 63;
    int b = bg * 64 + lane;
    int s = chunk * CHUNK + s_local;
    float4 xv = *(const float4*)(x + ((size_t)b * 1024 + s) * 4);
    float4 mv = *(const float4*)(meta + b * 4);
    _Float16* outp = xgt + (size_t)s_local * 196608 + b;
    int n0 = wv * 384;
    for (int n = n0; n < n0 + 384; n++) {
        const float* wr = Wg + n * 8;
        float v = Wg[6144 + n]
                + xv.x * wr[0] + xv.y * wr[1] + xv.z * wr[2] + xv.w * wr[3]
                + mv.x * wr[4] + mv.y * wr[5] + mv.z * wr[6] + mv.w * wr[7];
        outp[(size_t)n * 256] = (_Float16)v;
    }
}

// ---------- phaseB1: xg1t[s][g][b] = h0 @ Wih1^T + bih1 (LDS-free MFMA) ----------
__global__ __launch_bounds__(256) void phaseB1_kernel(
    const _Float16* __restrict__ houtfrag, const _Float16* __restrict__ Wi1frag,
    const float* __restrict__ bih1, _Float16* __restrict__ xgt) {
    int tid = threadIdx.x, wv = tid >> 6, lane = tid & 63;
    int q = lane >> 4, lm = lane & 15;
    int t16 = blockIdx.x * 2;                    // two 16-row m-tiles per block
    float bias[12];
#pragma unroll
    for (int j = 0; j < 12; j++) bias[j] = bih1[(wv * 12 + j) * 16 + lm];
    f32x4 acc[2][12] = {};
#pragma unroll
    for (int kt = 0; kt < 8; kt++) {
        half8 af[2], bf[12];
#pragma unroll
        for (int i = 0; i < 2; i++)
            af[i] = *(const half8*)(houtfrag + (size_t)((t16 + i) * 8 + kt) * 512 + lane * 8);
#pragma unroll
        for (int j = 0; j < 12; j++)
            bf[j] = *(const half8*)(Wi1frag + (size_t)((kt * 48 + wv * 12 + j) * 64 + lane) * 8);
#pragma unroll
        for (int i = 0; i < 2; i++)
#pragma unroll
            for (int j = 0; j < 12; j++)
                acc[i][j] = __builtin_amdgcn_mfma_f32_16x16x32_f16(af[i], bf[j], acc[i][j], 0, 0, 0);
    }
#pragma unroll
    for (int i = 0; i < 2; i++) {
        int t = t16 + i, s_local = t >> 4, b0 = (t & 15) * 16 + 4 * q;
#pragma unroll
        for (int j = 0; j < 12; j++) {
            int n = (wv * 12 + j) * 16 + lm;
            half4_t v;
#pragma unroll
            for (int r = 0; r < 4; r++) v[r] = (_Float16)(acc[i][j][r] + bias[j]);
            *(half4_t*)(xgt + (size_t)(s_local * 768 + n) * 256 + b0) = v;
        }
    }
}

// ---------- recurrence (both layers) ----------
// flags: bit0 = write houtfrag (layer 0), bit1 = final FC (layer 1, last chunk)
__global__ __launch_bounds__(512) void recur_kernel(
    const _Float16* __restrict__ Wfrag, const float* __restrict__ bhh,
    const _Float16* __restrict__ xgt, float* __restrict__ hstateF,
    _Float16* __restrict__ houtfrag, const float* __restrict__ fcW,
    const float* __restrict__ fcb, float* __restrict__ out,
    int chunk, int flags) {
    __shared__ _Float16 shA[8 * 520];   // h in A-frag layout, per-kt stride 520 f16 (+16B pad)
    __shared__ float shred[2048];
    const int tid = threadIdx.x, w = tid >> 6, lane = tid & 63;
    const int q = lane >> 4, lm = lane & 15;
    const int blk = blockIdx.x, bm = blk * 16;

    int nt[6];
    nt[0] = 2 * w;      nt[1] = 2 * w + 1;
    nt[2] = 16 + 2 * w; nt[3] = 17 + 2 * w;
    nt[4] = 32 + 2 * w; nt[5] = 33 + 2 * w;

    // resident weights: 48 B-fragments (192 regs -> AGPR-friendly, MFMA-native)
    half8 Bf[48];
#pragma unroll
    for (int kt = 0; kt < 8; kt++)
#pragma unroll
        for (int t = 0; t < 6; t++)
            Bf[kt * 6 + t] = *(const half8*)(Wfrag + (size_t)((kt * 48 + nt[t]) * 64 + lane) * 8);

    float bb[6];
#pragma unroll
    for (int t = 0; t < 6; t++) bb[t] = bhh[nt[t] * 16 + lm];

    // h state: register-resident, lane owns (m=4q+r, j=32w+16*tp+lm)
    float hreg[2][4];
    if (chunk == 0) {
#pragma unroll
        for (int tp = 0; tp < 2; tp++)
#pragma unroll
            for (int r = 0; r < 4; r++) hreg[tp][r] = 0.f;
    } else {
        f32x4 v0 = *(const f32x4*)(hstateF + (size_t)((blk * 8 + w) * 64 + lane) * 8);
        f32x4 v1 = *(const f32x4*)(hstateF + (size_t)((blk * 8 + w) * 64 + lane) * 8 + 4);
#pragma unroll
        for (int r = 0; r < 4; r++) { hreg[0][r] = v0[r]; hreg[1][r] = v1[r]; }
    }

    // seed shA from hreg (A-frag layout scatter)
#pragma unroll
    for (int tp = 0; tp < 2; tp++)
#pragma unroll
        for (int r = 0; r < 4; r++)
            shA[w * 520 + ((2 * tp + (lm >> 3)) * 16 + 4 * q + r) * 8 + (lm & 7)] =
                (_Float16)hreg[tp][r];
    __syncthreads();

    // xg pointers (xgt[s][n][b] layout)
    const _Float16* xp[6];
#pragma unroll
    for (int t = 0; t < 6; t++)
        xp[t] = xgt + (size_t)(nt[t] * 16 + lm) * 256 + bm + 4 * q;

    for (int s = 0; s < CHUNK; s++) {
        const size_t so = (size_t)s * 196608;
        half4_t xr4[6];
#pragma unroll
        for (int t = 0; t < 6; t++) xr4[t] = *(const half4_t*)(xp[t] + so);

        f32x4 acc[6] = {};
#pragma unroll
        for (int kt = 0; kt < 8; kt++) {
            half8 af = *(const half8*)(shA + kt * 520 + lane * 8);
#pragma unroll
            for (int t = 0; t < 6; t++)
                acc[t] = __builtin_amdgcn_mfma_f32_16x16x32_f16(af, Bf[kt * 6 + t], acc[t], 0, 0, 0);
        }
        __syncthreads();   // all A-reads complete before scatter overwrites

#pragma unroll
        for (int tp = 0; tp < 2; tp++) {
#pragma unroll
            for (int r = 0; r < 4; r++) {
                float xr = (float)xr4[tp][r];
                float xz = (float)xr4[2 + tp][r];
                float xn = (float)xr4[4 + tp][r];
                float hr = acc[tp][r] + bb[tp];
                float hz = acc[2 + tp][r] + bb[2 + tp];
                float hn = acc[4 + tp][r] + bb[4 + tp];
                float rr = sigf(xr + hr);
                float zz = sigf(xz + hz);
                float nn = tanh_(xn + rr * hn);
                float h = (1.f - zz) * nn + zz * hreg[tp][r];
                hreg[tp][r] = h;
                shA[w * 520 + ((2 * tp + (lm >> 3)) * 16 + 4 * q + r) * 8 + (lm & 7)] =
                    (_Float16)h;
            }
        }
        __syncthreads();   // scatter visible to all waves

        if (flags & 1) {   // stream h0 (frag layout) for phaseB1
            half8 v = *(const half8*)(shA + w * 520 + lane * 8);
            *(half8*)(houtfrag + (size_t)((s * 16 + blk) * 8 + w) * 512 + lane * 8) = v;
        }
    }

    // persist h state
    {
        f32x4 v0, v1;
#pragma unroll
        for (int r = 0; r < 4; r++) { v0[r] = hreg[0][r]; v1[r] = hreg[1][r]; }
        *(f32x4*)(hstateF + (size_t)((blk * 8 + w) * 64 + lane) * 8) = v0;
        *(f32x4*)(hstateF + (size_t)((blk * 8 + w) * 64 + lane) * 8 + 4) = v1;
    }

    if (flags & 2) {   // final FC: out[b] = h2 . fcW + fcb
        float fw0 = fcW[32 * w + lm], fw1 = fcW[32 * w + 16 + lm];
        f32x4 p;
#pragma unroll
        for (int r = 0; r < 4; r++) p[r] = hreg[0][r] * fw0 + hreg[1][r] * fw1;
        *(f32x4*)(shred + (size_t)(w * 64 + lane) * 4) = p;
        __syncthreads();
        if (tid < 16) {
            int m = tid, qq = m >> 2, rr2 = m & 3;
            float a = fcb[0];
            for (int ww = 0; ww < 8; ww++)
                for (int l2 = 0; l2 < 16; l2++)
                    a += shred[(ww * 64 + qq * 16 + l2) * 4 + rr2];
            out[bm + m] = a;
        }
    }
}

extern "C" void kernel_launch(void* const* d_in, const int* in_sizes, int n_in,
                              void* d_out, int out_size, void* d_ws, size_t ws_size,
                              hipStream_t stream) {
    const float* x    = (const float*)d_in[0];
    const float* meta = (const float*)d_in[1];
    const float* Wih0 = (const float*)d_in[2];
    const float* Whh0 = (const float*)d_in[3];
    const float* bih0 = (const float*)d_in[4];
    const float* bhh0 = (const float*)d_in[5];
    const float* Wih1 = (const float*)d_in[6];
    const float* Whh1 = (const float*)d_in[7];
    const float* bih1 = (const float*)d_in[8];
    const float* bhh1 = (const float*)d_in[9];
    const float* fcW  = (const float*)d_in[10];
    const float* fcb  = (const float*)d_in[11];
    float* out = (float*)d_out;

    char* ws = (char*)d_ws;
    _Float16* Wfrag0   = (_Float16*)(ws + 0);
    _Float16* Wfrag1   = (_Float16*)(ws + 393216);
    _Float16* Wi1frag  = (_Float16*)(ws + 786432);
    float*    hstateF0 = (float*)(ws + 1179648);
    float*    hstateF1 = (float*)(ws + 1441792);
    _Float16* houtfrag = (_Float16*)(ws + 1703936);
    _Float16* xgt      = (_Float16*)(ws + 18481152);

    prep_kernel<<<288, 256, 0, stream>>>(Whh0, Whh1, Wih1, Wfrag0, Wfrag1, Wi1frag);

    for (int c = 0; c < NCHUNK; c++) {
        phaseB0_kernel<<<512, 128, 0, stream>>>(x, meta, Wih0, bih0, xgt, c);
        recur_kernel<<<16, 512, 0, stream>>>(Wfrag0, bhh0, xgt, hstateF0, houtfrag,
                                             fcW, fcb, out, c, 1);
        phaseB1_kernel<<<1024, 256, 0, stream>>>(houtfrag, Wi1frag, bih1, xgt);
        recur_kernel<<<16, 512, 0, stream>>>(Wfrag1, bhh1, xgt, hstateF1, houtfrag,
                                             fcW, fcb, out, c, (c == NCHUNK - 1) ? 2 : 0);
    }
}

// Round 6
// 4907.381 us; speedup vs baseline: 1.9221x; 1.9221x over previous
//
#include <hip/hip_runtime.h>
#include <hip/hip_fp16.h>

// GRUPK R6: MFMA recurrence, latency-fixed.
// R5 failure: 16 blocks (1.5% occupancy) + per-step barrier-serialized xg loads
// (~900cy HBM latency, 2 waves/SIMD) -> 10560 cy/step vs 930 cy MFMA floor.
// R6: (1) fused L0/L1 kernel, 32 blocks: blocks 0-15 = layer0 chunk c,
//     blocks 16-31 = layer1 chunk c-1 (cross-chunk software pipeline);
//     (2) register prefetch of next step's xg (issued pre-barrier);
//     (3) double-buffered shA -> 1 barrier/step;
//     (4) CHUNK=64 so xg0t+xg1t coexist in ws (60.4MB total).
//
// ws layout (bytes):
//   0         Wfrag0   [8 kt][48 nt][64 lane][8] f16    393216
//   393216    Wfrag1                                    393216
//   786432    Wi1frag                                   393216
//   1179648   hstateF0 f32 [16 blk][8 w][64][8]         262144
//   1441792   hstateF1                                  262144
//   1703936   houtfrag f16 [64 s][16 btile][8 w][512]   8388608
//   10092544  xg0t     f16 [64 s][768 g][256 b]         25165824
//   35258368  xg1t     f16 [64 s][768 g][256 b]         25165824
//   total 60424192

#define SCH 64
#define NCH 16

typedef _Float16 half8 __attribute__((ext_vector_type(8)));
typedef _Float16 half4_t __attribute__((ext_vector_type(4)));
typedef float f32x4 __attribute__((ext_vector_type(4)));

__device__ __forceinline__ float sigf(float v) {
    return 1.f / (1.f + __expf(-v));
}
__device__ __forceinline__ float tanh_(float v) {
    float a = fabsf(v);
    float e = __expf(-2.f * a);
    float r = (1.f - e) / (1.f + e);
    return copysignf(r, v);
}

// ---------- prep: W -> MFMA B-fragment layout [kt][nt][lane][8] f16 ----------
__global__ __launch_bounds__(256) void prep_kernel(
    const float* __restrict__ Whh0, const float* __restrict__ Whh1,
    const float* __restrict__ Wih1,
    _Float16* __restrict__ Wfrag0, _Float16* __restrict__ Wfrag1,
    _Float16* __restrict__ Wi1frag) {
    int tid = blockIdx.x * 256 + threadIdx.x;     // 3 * 24576 = 73728
    int mat = tid / 24576;
    int r   = tid % 24576;                        // = (kt*48 + nt)*64 + lane
    int kt   = r / 3072;
    int rem  = r % 3072;
    int nt   = rem >> 6;
    int lane = rem & 63;
    int n = nt * 16 + (lane & 15);
    int k = kt * 32 + (lane >> 4) * 8;
    const float* src = (mat == 0 ? Whh0 : (mat == 1 ? Whh1 : Wih1)) + n * 256 + k;
    _Float16* dst = (mat == 0 ? Wfrag0 : (mat == 1 ? Wfrag1 : Wi1frag)) + (size_t)r * 8;
#pragma unroll
    for (int j = 0; j < 8; j++) dst[j] = (_Float16)src[j];
}

// ---------- phaseB0: xg0t[s][g][b] = [x|meta] @ Wih0^T + bih0 ----------
__global__ __launch_bounds__(128) void phaseB0_kernel(
    const float* __restrict__ x, const float* __restrict__ meta,
    const float* __restrict__ Wih0, const float* __restrict__ bih0,
    _Float16* __restrict__ xg0t, int chunk) {
    __shared__ float Wg[768 * 8 + 768];   // rows + bias
    int tid = threadIdx.x;
    for (int i = tid; i < 6912; i += 128)
        Wg[i] = (i < 6144) ? Wih0[i] : bih0[i - 6144];
    __syncthreads();
    int s_local = blockIdx.x >> 2, bg = blockIdx.x & 3;   // 256 blocks: 64 s x 4 bg
    int wv = tid >> 6, lane = tid & 63;
    int b = bg * 64 + lane;
    int s = chunk * SCH + s_local;
    float4 xv = *(const float4*)(x + ((size_t)b * 1024 + s) * 4);
    float4 mv = *(const float4*)(meta + b * 4);
    _Float16* outp = xg0t + (size_t)s_local * 196608 + b;
    int n0 = wv * 384;
    for (int n = n0; n < n0 + 384; n++) {
        const float* wr = Wg + n * 8;
        float v = Wg[6144 + n]
                + xv.x * wr[0] + xv.y * wr[1] + xv.z * wr[2] + xv.w * wr[3]
                + mv.x * wr[4] + mv.y * wr[5] + mv.z * wr[6] + mv.w * wr[7];
        outp[(size_t)n * 256] = (_Float16)v;
    }
}

// ---------- phaseB1: xg1t[s][g][b] = h0 @ Wih1^T + bih1 (LDS-free MFMA) ----------
__global__ __launch_bounds__(256) void phaseB1_kernel(
    const _Float16* __restrict__ houtfrag, const _Float16* __restrict__ Wi1frag,
    const float* __restrict__ bih1, _Float16* __restrict__ xg1t) {
    int tid = threadIdx.x, wv = tid >> 6, lane = tid & 63;
    int q = lane >> 4, lm = lane & 15;
    int t16 = blockIdx.x * 2;                    // 512 blocks x 2 m-tiles (1024 tiles)
    float bias[12];
#pragma unroll
    for (int j = 0; j < 12; j++) bias[j] = bih1[(wv * 12 + j) * 16 + lm];
    f32x4 acc[2][12] = {};
#pragma unroll
    for (int kt = 0; kt < 8; kt++) {
        half8 af[2], bf[12];
#pragma unroll
        for (int i = 0; i < 2; i++)
            af[i] = *(const half8*)(houtfrag + (size_t)((t16 + i) * 8 + kt) * 512 + lane * 8);
#pragma unroll
        for (int j = 0; j < 12; j++)
            bf[j] = *(const half8*)(Wi1frag + (size_t)((kt * 48 + wv * 12 + j) * 64 + lane) * 8);
#pragma unroll
        for (int i = 0; i < 2; i++)
#pragma unroll
            for (int j = 0; j < 12; j++)
                acc[i][j] = __builtin_amdgcn_mfma_f32_16x16x32_f16(af[i], bf[j], acc[i][j], 0, 0, 0);
    }
#pragma unroll
    for (int i = 0; i < 2; i++) {
        int t = t16 + i, s_local = t >> 4, b0 = (t & 15) * 16 + 4 * q;
#pragma unroll
        for (int j = 0; j < 12; j++) {
            int n = (wv * 12 + j) * 16 + lm;
            half4_t v;
#pragma unroll
            for (int r = 0; r < 4; r++) v[r] = (_Float16)(acc[i][j][r] + bias[j]);
            *(half4_t*)(xg1t + (size_t)(s_local * 768 + n) * 256 + b0) = v;
        }
    }
}

// ---------- fused recurrence: blocks 0-15 = L0 chunk c, 16-31 = L1 chunk c-1 ----------
__global__ __launch_bounds__(512) void recur_kernel(
    const _Float16* __restrict__ Wfrag0, const float* __restrict__ bhh0,
    const _Float16* __restrict__ xg0t, float* __restrict__ hstateF0,
    const _Float16* __restrict__ Wfrag1, const float* __restrict__ bhh1,
    const _Float16* __restrict__ xg1t, float* __restrict__ hstateF1,
    _Float16* __restrict__ houtfrag, const float* __restrict__ fcW,
    const float* __restrict__ fcb, float* __restrict__ out, int c) {
    const int role = blockIdx.x >> 4;
    if (role == 0 && c == NCH) return;   // tail launch: no L0 work
    if (role == 1 && c == 0) return;     // first launch: no L1 work yet
    const int cc = role ? c - 1 : c;     // this block's chunk index
    const _Float16* Wfrag = role ? Wfrag1 : Wfrag0;
    const float* bhh      = role ? bhh1 : bhh0;
    const _Float16* xgt   = role ? xg1t : xg0t;
    float* hstateF        = role ? hstateF1 : hstateF0;
    const bool doHout = (role == 0);
    const bool doFC   = (role == 1) && (cc == NCH - 1);

    __shared__ _Float16 shA[2 * 4160];   // double-buffered h in A-frag layout (8 kt x 520)
    __shared__ float shred[2048];
    const int tid = threadIdx.x, w = tid >> 6, lane = tid & 63;
    const int q = lane >> 4, lm = lane & 15;
    const int blk = blockIdx.x & 15, bm = blk * 16;

    int nt[6];
    nt[0] = 2 * w;      nt[1] = 2 * w + 1;
    nt[2] = 16 + 2 * w; nt[3] = 17 + 2 * w;
    nt[4] = 32 + 2 * w; nt[5] = 33 + 2 * w;

    // resident weights: 48 B-fragments (MFMA reads AGPR operands natively)
    half8 Bf[48];
#pragma unroll
    for (int kt = 0; kt < 8; kt++)
#pragma unroll
        for (int t = 0; t < 6; t++)
            Bf[kt * 6 + t] = *(const half8*)(Wfrag + (size_t)((kt * 48 + nt[t]) * 64 + lane) * 8);

    float bb[6];
#pragma unroll
    for (int t = 0; t < 6; t++) bb[t] = bhh[nt[t] * 16 + lm];

    // h state: register-resident, lane owns (m=4q+r, j=32w+16*tp+lm)
    float hreg[2][4];
    if (cc == 0) {
#pragma unroll
        for (int tp = 0; tp < 2; tp++)
#pragma unroll
            for (int r = 0; r < 4; r++) hreg[tp][r] = 0.f;
    } else {
        f32x4 v0 = *(const f32x4*)(hstateF + (size_t)((blk * 8 + w) * 64 + lane) * 8);
        f32x4 v1 = *(const f32x4*)(hstateF + (size_t)((blk * 8 + w) * 64 + lane) * 8 + 4);
#pragma unroll
        for (int r = 0; r < 4; r++) { hreg[0][r] = v0[r]; hreg[1][r] = v1[r]; }
    }

    // seed buffer 0 with h (A-frag layout scatter)
#pragma unroll
    for (int tp = 0; tp < 2; tp++)
#pragma unroll
        for (int r = 0; r < 4; r++)
            shA[w * 520 + ((2 * tp + (lm >> 3)) * 16 + 4 * q + r) * 8 + (lm & 7)] =
                (_Float16)hreg[tp][r];

    // xg pointers (xgt[s][n][b] layout) + preload step 0
    const _Float16* xp[6];
#pragma unroll
    for (int t = 0; t < 6; t++)
        xp[t] = xgt + (size_t)(nt[t] * 16 + lm) * 256 + bm + 4 * q;
    half4_t xcur[6];
#pragma unroll
    for (int t = 0; t < 6; t++) xcur[t] = *(const half4_t*)(xp[t]);

    __syncthreads();

    for (int s = 0; s < SCH; s++) {
        const int p = s & 1;
        f32x4 acc[6] = {};
#pragma unroll
        for (int kt = 0; kt < 8; kt++) {
            half8 af = *(const half8*)(shA + p * 4160 + kt * 520 + lane * 8);
#pragma unroll
            for (int t = 0; t < 6; t++)
                acc[t] = __builtin_amdgcn_mfma_f32_16x16x32_f16(af, Bf[kt * 6 + t], acc[t], 0, 0, 0);
        }

        // nonlinearity per-lane (uses xcur loaded last iteration)
#pragma unroll
        for (int tp = 0; tp < 2; tp++) {
#pragma unroll
            for (int r = 0; r < 4; r++) {
                float xr = (float)xcur[tp][r];
                float xz = (float)xcur[2 + tp][r];
                float xn = (float)xcur[4 + tp][r];
                float hr = acc[tp][r] + bb[tp];
                float hz = acc[2 + tp][r] + bb[2 + tp];
                float hn = acc[4 + tp][r] + bb[4 + tp];
                float rr = sigf(xr + hr);
                float zz = sigf(xz + hz);
                float nn = tanh_(xn + rr * hn);
                float h = nn + zz * (hreg[tp][r] - nn);
                hreg[tp][r] = h;
                shA[(p ^ 1) * 4160 + w * 520 +
                    ((2 * tp + (lm >> 3)) * 16 + 4 * q + r) * 8 + (lm & 7)] = (_Float16)h;
            }
        }

        // prefetch next step's xg (in flight across the barrier)
        {
            const size_t so = (size_t)(s + 1 < SCH ? s + 1 : s) * 196608;
#pragma unroll
            for (int t = 0; t < 6; t++) xcur[t] = *(const half4_t*)(xp[t] + so);
        }

        __syncthreads();   // h' scatter visible; next iter reads buf p^1

        if (doHout) {      // stream h0 (frag layout) for phaseB1
            half8 v = *(const half8*)(shA + (p ^ 1) * 4160 + w * 520 + lane * 8);
            *(half8*)(houtfrag + (size_t)((s * 16 + blk) * 8 + w) * 512 + lane * 8) = v;
        }
    }

    // persist h state
    {
        f32x4 v0, v1;
#pragma unroll
        for (int r = 0; r < 4; r++) { v0[r] = hreg[0][r]; v1[r] = hreg[1][r]; }
        *(f32x4*)(hstateF + (size_t)((blk * 8 + w) * 64 + lane) * 8) = v0;
        *(f32x4*)(hstateF + (size_t)((blk * 8 + w) * 64 + lane) * 8 + 4) = v1;
    }

    if (doFC) {   // final FC: out[b] = h2 . fcW + fcb
        float fw0 = fcW[32 * w + lm], fw1 = fcW[32 * w + 16 + lm];
        f32x4 pv;
#pragma unroll
        for (int r = 0; r < 4; r++) pv[r] = hreg[0][r] * fw0 + hreg[1][r] * fw1;
        *(f32x4*)(shred + (size_t)(w * 64 + lane) * 4) = pv;
        __syncthreads();
        if (tid < 16) {
            int m = tid, qq = m >> 2, rr2 = m & 3;
            float a = fcb[0];
            for (int ww = 0; ww < 8; ww++)
                for (int l2 = 0; l2 < 16; l2++)
                    a += shred[(ww * 64 + qq * 16 + l2) * 4 + rr2];
            out[bm + m] = a;
        }
    }
}

extern "C" void kernel_launch(void* const* d_in, const int* in_sizes, int n_in,
                              void* d_out, int out_size, void* d_ws, size_t ws_size,
                              hipStream_t stream) {
    const float* x    = (const float*)d_in[0];
    const float* meta = (const float*)d_in[1];
    const float* Wih0 = (const float*)d_in[2];
    const float* Whh0 = (const float*)d_in[3];
    const float* bih0 = (const float*)d_in[4];
    const float* bhh0 = (const float*)d_in[5];
    const float* Wih1 = (const float*)d_in[6];
    const float* Whh1 = (const float*)d_in[7];
    const float* bih1 = (const float*)d_in[8];
    const float* bhh1 = (const float*)d_in[9];
    const float* fcW  = (const float*)d_in[10];
    const float* fcb  = (const float*)d_in[11];
    float* out = (float*)d_out;

    char* ws = (char*)d_ws;
    _Float16* Wfrag0   = (_Float16*)(ws + 0);
    _Float16* Wfrag1   = (_Float16*)(ws + 393216);
    _Float16* Wi1frag  = (_Float16*)(ws + 786432);
    float*    hstateF0 = (float*)(ws + 1179648);
    float*    hstateF1 = (float*)(ws + 1441792);
    _Float16* houtfrag = (_Float16*)(ws + 1703936);
    _Float16* xg0t     = (_Float16*)(ws + 10092544);
    _Float16* xg1t     = (_Float16*)(ws + 35258368);

    prep_kernel<<<288, 256, 0, stream>>>(Whh0, Whh1, Wih1, Wfrag0, Wfrag1, Wi1frag);

    for (int c = 0; c <= NCH; c++) {
        if (c < NCH) phaseB0_kernel<<<256, 128, 0, stream>>>(x, meta, Wih0, bih0, xg0t, c);
        recur_kernel<<<32, 512, 0, stream>>>(Wfrag0, bhh0, xg0t, hstateF0,
                                             Wfrag1, bhh1, xg1t, hstateF1,
                                             houtfrag, fcW, fcb, out, c);
        if (c < NCH) phaseB1_kernel<<<512, 256, 0, stream>>>(houtfrag, Wi1frag, bih1, xg1t);
    }
}

// Round 7
// 3008.113 us; speedup vs baseline: 3.1357x; 1.6314x over previous
//
#include <hip/hip_runtime.h>
#include <hip/hip_fp16.h>

// GRUPK R7: MFMA recurrence with register-resident weights, take 2.
// R6 failure mode (proven by VGPR_Count=128 + 9200cy/step): allocator budgeted
// 128 regs/wave (high-occupancy default), so the 192-reg Bf weight array was
// rematerialized from L2 inside the K-loop every step. Also FETCH=102MB = 2x
// the 50MB of xg actually needed (8B loads touching 32B of each 64B line).
// R7: (1) amdgpu_waves_per_eu(2,2) -> 256-reg budget (R2 evidence: min-waves
//     sets the budget exactly); demand trimmed to ~250 by folding bhh(r,z)
//     into phaseB biases; Bf+acc live in AGPRs (MFMA-native operands).
// (2) lane-major xg layout [s][blk32][w8][lane32][24]: per-lane 48B contiguous
//     (3x dwordx4), wave reads 1536B contiguous -> zero overfetch.
// (3) 8 batches/block -> 32 blocks/layer, 64 CUs; fused L0(c)/L1(c-1) pipeline.
//
// ws layout (bytes):
//   0         Wfrag0   [8 kt][48 nt][64 lane][8] f16   393216
//   393216    Wfrag1                                   393216
//   786432    Wi1frag                                  393216
//   1179648   hst0     f32 [32 blk][8 w][64 lane][8]   524288
//   1703936   hst1                                     524288
//   2228224   houtfrag f16 [64 s][32 blk][8 kt][32][8] 8388608
//   10616832  xg0t     f16 [64 s][32 blk][8 w][32][24] 25165824
//   35782656  xg1t                                     25165824
//   total 60948480

#define SCH 64
#define NCH 16

typedef _Float16 half8 __attribute__((ext_vector_type(8)));
typedef _Float16 half4_t __attribute__((ext_vector_type(4)));
typedef float f32x4 __attribute__((ext_vector_type(4)));

__device__ __forceinline__ float rcp_(float x) {
#if __has_builtin(__builtin_amdgcn_rcpf)
    return __builtin_amdgcn_rcpf(x);
#else
    return 1.f / x;
#endif
}
__device__ __forceinline__ float exp2_(float x) {
#if __has_builtin(__builtin_amdgcn_exp2f)
    return __builtin_amdgcn_exp2f(x);
#else
    return exp2f(x);
#endif
}
// sig(v) = 1/(1+e^-v); e^-v=Inf -> 0, e^-v=0 -> 1  (safe at extremes)
__device__ __forceinline__ float sigf(float v) {
    return rcp_(1.f + exp2_(v * -1.442695041f));
}
// tanh(v) = 1 - 2/(e^{2v}+1); e^{2v}=Inf -> 1, ->0 -> -1  (safe at extremes)
__device__ __forceinline__ float tanh_(float v) {
    return 1.f - 2.f * rcp_(1.f + exp2_(v * 2.885390082f));
}

// ---------- prep: W -> MFMA B-fragment layout [kt][nt][lane][8] f16 ----------
__global__ __launch_bounds__(256) void prep_kernel(
    const float* __restrict__ Whh0, const float* __restrict__ Whh1,
    const float* __restrict__ Wih1,
    _Float16* __restrict__ Wfrag0, _Float16* __restrict__ Wfrag1,
    _Float16* __restrict__ Wi1frag) {
    int tid = blockIdx.x * 256 + threadIdx.x;     // 3 * 24576 = 73728
    int mat = tid / 24576;
    int r   = tid % 24576;                        // = (kt*48 + nt)*64 + lane
    int kt   = r / 3072;
    int rem  = r % 3072;
    int nt   = rem >> 6;
    int lane = rem & 63;
    int n = nt * 16 + (lane & 15);
    int k = kt * 32 + (lane >> 4) * 8;
    const float* src = (mat == 0 ? Whh0 : (mat == 1 ? Whh1 : Wih1)) + n * 256 + k;
    _Float16* dst = (mat == 0 ? Wfrag0 : (mat == 1 ? Wfrag1 : Wi1frag)) + (size_t)r * 8;
#pragma unroll
    for (int j = 0; j < 8; j++) dst[j] = (_Float16)src[j];
}

// ---------- phaseB0: xg0t (lane-major layout) = [x|meta] @ Wih0^T + bih0 (+bhh0 r,z) ----------
__global__ __launch_bounds__(256) void phaseB0_kernel(
    const float* __restrict__ x, const float* __restrict__ meta,
    const float* __restrict__ Wih0, const float* __restrict__ bih0,
    const float* __restrict__ bhh0, _Float16* __restrict__ xg0t, int chunk) {
    __shared__ float Wb[6144];
    __shared__ float Bb[768];
    const int t = threadIdx.x;
    const int sq = blockIdx.x;    // 4 quarters of 16 steps
    const int blk = blockIdx.y;   // 32 batch-octets
    for (int i = t; i < 6144; i += 256) Wb[i] = Wih0[i];
    for (int i = t; i < 768; i += 256) Bb[i] = bih0[i] + (i < 512 ? bhh0[i] : 0.f);
    __syncthreads();
    const int w = t >> 5, l32 = t & 31;
    const int qc = l32 >> 4, lm = l32 & 15;

    float Wr[6][8], br[6];
#pragma unroll
    for (int g3 = 0; g3 < 3; g3++)
#pragma unroll
        for (int tp = 0; tp < 2; tp++) {
            int n = g3 * 256 + 32 * w + 16 * tp + lm;
            int j6 = g3 * 2 + tp;
#pragma unroll
            for (int kk = 0; kk < 8; kk++) Wr[j6][kk] = Wb[n * 8 + kk];
            br[j6] = Bb[n];
        }
    const int b0 = blk * 8 + qc * 4;
    float4 mv[4];
#pragma unroll
    for (int r = 0; r < 4; r++) mv[r] = *(const float4*)(meta + (b0 + r) * 4);

    for (int sl = 0; sl < 16; sl++) {
        int s_local = sq * 16 + sl;
        int s = chunk * SCH + s_local;
        float4 xv[4];
#pragma unroll
        for (int r = 0; r < 4; r++)
            xv[r] = *(const float4*)(x + ((size_t)(b0 + r) * 1024 + s) * 4);
        half8 o[3];
#pragma unroll
        for (int g3 = 0; g3 < 3; g3++)
#pragma unroll
            for (int tp = 0; tp < 2; tp++) {
                int j6 = g3 * 2 + tp;
#pragma unroll
                for (int r = 0; r < 4; r++) {
                    float v = br[j6]
                        + xv[r].x * Wr[j6][0] + xv[r].y * Wr[j6][1]
                        + xv[r].z * Wr[j6][2] + xv[r].w * Wr[j6][3]
                        + mv[r].x * Wr[j6][4] + mv[r].y * Wr[j6][5]
                        + mv[r].z * Wr[j6][6] + mv[r].w * Wr[j6][7];
                    o[g3][tp * 4 + r] = (_Float16)v;
                }
            }
        _Float16* dst = xg0t + (((size_t)(s_local * 32 + blk) * 8 + w) * 32 + l32) * 24;
        *(half8*)(dst)      = o[0];
        *(half8*)(dst + 8)  = o[1];
        *(half8*)(dst + 16) = o[2];
    }
}

// ---------- phaseB1: xg1t (lane-major) = h0 @ Wih1^T + bih1 (+bhh1 r,z) ----------
__global__ __launch_bounds__(256) void phaseB1_kernel(
    const _Float16* __restrict__ houtfrag, const _Float16* __restrict__ Wi1frag,
    const float* __restrict__ bih1, const float* __restrict__ bhh1,
    _Float16* __restrict__ xg1t) {
    const int tid = threadIdx.x, wv = tid >> 6, lane = tid & 63;
    const int q = lane >> 4, lm = lane & 15;
    const int t16 = blockIdx.x * 2;              // 512 blocks x 2 m-tiles
    const int asel = (lane >> 3) & 1;            // producer block parity for A rows
    const int cidx = (lane >> 4) * 8 + (lane & 7);

    float bias[12];
#pragma unroll
    for (int j = 0; j < 12; j++) {
        int n = (wv * 12 + j) * 16 + lm;
        bias[j] = bih1[n] + (n < 512 ? bhh1[n] : 0.f);
    }
    f32x4 acc[2][12] = {};
#pragma unroll
    for (int kt = 0; kt < 8; kt++) {
        half8 af[2], bf[12];
#pragma unroll
        for (int i = 0; i < 2; i++) {
            int tt = t16 + i, s = tt >> 4, bt = tt & 15;
            af[i] = *(const half8*)(houtfrag +
                (((size_t)(s * 32 + bt * 2 + asel) * 8 + kt) * 32 + cidx) * 8);
        }
#pragma unroll
        for (int j = 0; j < 12; j++)
            bf[j] = *(const half8*)(Wi1frag + (size_t)((kt * 48 + wv * 12 + j) * 64 + lane) * 8);
#pragma unroll
        for (int i = 0; i < 2; i++)
#pragma unroll
            for (int j = 0; j < 12; j++)
                acc[i][j] = __builtin_amdgcn_mfma_f32_16x16x32_f16(af[i], bf[j], acc[i][j], 0, 0, 0);
    }
#pragma unroll
    for (int i = 0; i < 2; i++) {
        int tt = t16 + i, s = tt >> 4, bt = tt & 15;
        int blk = bt * 2 + (q >> 1), qc = q & 1;
#pragma unroll
        for (int j = 0; j < 12; j++) {
            int n = (wv * 12 + j) * 16 + lm;
            int g3 = n >> 8, nn = n & 255;
            int wc = nn >> 5, tp = (nn >> 4) & 1, lmc = nn & 15;
            half4_t v;
#pragma unroll
            for (int r = 0; r < 4; r++) v[r] = (_Float16)(acc[i][j][r] + bias[j]);
            *(half4_t*)(xg1t + (((size_t)(s * 32 + blk) * 8 + wc) * 32 + qc * 16 + lmc) * 24
                             + g3 * 8 + tp * 4) = v;
        }
    }
}

// ---------- fused recurrence: blocks 0-31 = L0 chunk c, 32-63 = L1 chunk c-1 ----------
__global__
__attribute__((amdgpu_flat_work_group_size(512, 512), amdgpu_waves_per_eu(2, 2)))
void recur_kernel(
    const _Float16* __restrict__ Wfrag0, const float* __restrict__ bhh0,
    const _Float16* __restrict__ xg0t, float* __restrict__ hst0,
    const _Float16* __restrict__ Wfrag1, const float* __restrict__ bhh1,
    const _Float16* __restrict__ xg1t, float* __restrict__ hst1,
    _Float16* __restrict__ houtfrag, const float* __restrict__ fcW,
    const float* __restrict__ fcb, float* __restrict__ out, int c) {
    const int role = blockIdx.x >> 5;
    if (role == 0 && c == NCH) return;
    if (role == 1 && c == 0) return;
    const int cc = role ? c - 1 : c;
    const _Float16* Wfrag = role ? Wfrag1 : Wfrag0;
    const float* bhh      = role ? bhh1 : bhh0;
    const _Float16* xgt   = role ? xg1t : xg0t;
    float* hstate         = role ? hst1 : hst0;
    const bool doHout = (role == 0);
    const bool doFC   = (role == 1) && (cc == NCH - 1);

    __shared__ _Float16 shA[2 * 4160];   // double-buffered h, A-frag layout [kt][64 rows][8] (+pad)
    __shared__ float shred[2048];
    const int tid = threadIdx.x, w = tid >> 6, lane = tid & 63;
    const int q = lane >> 4, lm = lane & 15;
    const int blk = blockIdx.x & 31;

    int nt[6];
    nt[0] = 2 * w;      nt[1] = 2 * w + 1;
    nt[2] = 16 + 2 * w; nt[3] = 17 + 2 * w;
    nt[4] = 32 + 2 * w; nt[5] = 33 + 2 * w;

    // resident weights: 48 B-fragments = 192 regs (MFMA-native AGPR operands)
    half8 Bf[48];
#pragma unroll
    for (int kt = 0; kt < 8; kt++)
#pragma unroll
        for (int t = 0; t < 6; t++)
            Bf[kt * 6 + t] = *(const half8*)(Wfrag + (size_t)((kt * 48 + nt[t]) * 64 + lane) * 8);

    // only the n-gate bhh stays (r,z folded into xg biases)
    const float bbn0 = bhh[512 + 32 * w + lm];
    const float bbn1 = bhh[512 + 32 * w + 16 + lm];

    // h state: lane owns (m=4q+r, j=32w+16tp+lm); valid for q<2 (M=8)
    float hreg[2][4];
    if (cc == 0) {
#pragma unroll
        for (int tp = 0; tp < 2; tp++)
#pragma unroll
            for (int r = 0; r < 4; r++) hreg[tp][r] = 0.f;
    } else {
        f32x4 v0 = *(const f32x4*)(hstate + (size_t)((blk * 8 + w) * 64 + lane) * 8);
        f32x4 v1 = *(const f32x4*)(hstate + (size_t)((blk * 8 + w) * 64 + lane) * 8 + 4);
#pragma unroll
        for (int r = 0; r < 4; r++) { hreg[0][r] = v0[r]; hreg[1][r] = v1[r]; }
    }

    // seed shA[0] (A-frag scatter; q>=2 lanes fill garbage rows 8..15 harmlessly)
#pragma unroll
    for (int tp = 0; tp < 2; tp++)
#pragma unroll
        for (int r = 0; r < 4; r++)
            shA[w * 520 + ((2 * tp + (lm >> 3)) * 16 + 4 * q + r) * 8 + (lm & 7)] =
                (_Float16)hreg[tp][r];

    // xg: per-lane 48B contiguous; lanes 32..63 duplicate lanes 0..31 (results unused)
    const _Float16* xptr = xgt + ((size_t)blk * 8 + w) * 768 + (lane & 31) * 24;
    half8 xc0 = *(const half8*)(xptr);
    half8 xc1 = *(const half8*)(xptr + 8);
    half8 xc2 = *(const half8*)(xptr + 16);

    __syncthreads();

    for (int s = 0; s < SCH; s++) {
        const int p = s & 1;
        f32x4 acc[6] = {};
#pragma unroll
        for (int kt = 0; kt < 8; kt++) {
            half8 af = *(const half8*)(shA + p * 4160 + kt * 520 + lane * 8);
#pragma unroll
            for (int t = 0; t < 6; t++)
                acc[t] = __builtin_amdgcn_mfma_f32_16x16x32_f16(af, Bf[kt * 6 + t], acc[t], 0, 0, 0);
        }

#pragma unroll
        for (int tp = 0; tp < 2; tp++) {
            const float bbn = tp ? bbn1 : bbn0;
#pragma unroll
            for (int r = 0; r < 4; r++) {
                float rr = sigf((float)xc0[tp * 4 + r] + acc[tp][r]);
                float zz = sigf((float)xc1[tp * 4 + r] + acc[2 + tp][r]);
                float nn = tanh_((float)xc2[tp * 4 + r] + rr * (acc[4 + tp][r] + bbn));
                float h = nn + zz * (hreg[tp][r] - nn);
                hreg[tp][r] = h;
                shA[(p ^ 1) * 4160 + w * 520 +
                    ((2 * tp + (lm >> 3)) * 16 + 4 * q + r) * 8 + (lm & 7)] = (_Float16)h;
            }
        }

        // prefetch next step's xg (stays in flight across the barrier)
        xptr += 196608;
        xc0 = *(const half8*)(xptr);
        xc1 = *(const half8*)(xptr + 8);
        xc2 = *(const half8*)(xptr + 16);

        __syncthreads();

        if (doHout && (lane & 8) == 0) {   // compact copy of 32 valid rows
            half8 v = *(const half8*)(shA + (p ^ 1) * 4160 + w * 520 + lane * 8);
            *(half8*)(houtfrag +
                (((size_t)(s * 32 + blk) * 8 + w) * 32 + ((lane >> 4) * 8 + (lane & 7))) * 8) = v;
        }
    }

    // persist h state
    {
        f32x4 v0, v1;
#pragma unroll
        for (int r = 0; r < 4; r++) { v0[r] = hreg[0][r]; v1[r] = hreg[1][r]; }
        *(f32x4*)(hstate + (size_t)((blk * 8 + w) * 64 + lane) * 8) = v0;
        *(f32x4*)(hstate + (size_t)((blk * 8 + w) * 64 + lane) * 8 + 4) = v1;
    }

    if (doFC) {   // out[b] = h2 . fcW + fcb for this block's 8 batches
        float fw0 = fcW[32 * w + lm], fw1 = fcW[32 * w + 16 + lm];
        f32x4 pv;
#pragma unroll
        for (int r = 0; r < 4; r++) pv[r] = hreg[0][r] * fw0 + hreg[1][r] * fw1;
        *(f32x4*)(shred + (size_t)(w * 64 + lane) * 4) = pv;
        __syncthreads();
        if (tid < 8) {
            int qq = tid >> 2, rr2 = tid & 3;
            float a = fcb[0];
            for (int ww = 0; ww < 8; ww++)
                for (int l2 = 0; l2 < 16; l2++)
                    a += shred[(ww * 64 + qq * 16 + l2) * 4 + rr2];
            out[blk * 8 + tid] = a;
        }
    }
}

extern "C" void kernel_launch(void* const* d_in, const int* in_sizes, int n_in,
                              void* d_out, int out_size, void* d_ws, size_t ws_size,
                              hipStream_t stream) {
    const float* x    = (const float*)d_in[0];
    const float* meta = (const float*)d_in[1];
    const float* Wih0 = (const float*)d_in[2];
    const float* Whh0 = (const float*)d_in[3];
    const float* bih0 = (const float*)d_in[4];
    const float* bhh0 = (const float*)d_in[5];
    const float* Wih1 = (const float*)d_in[6];
    const float* Whh1 = (const float*)d_in[7];
    const float* bih1 = (const float*)d_in[8];
    const float* bhh1 = (const float*)d_in[9];
    const float* fcW  = (const float*)d_in[10];
    const float* fcb  = (const float*)d_in[11];
    float* out = (float*)d_out;

    char* ws = (char*)d_ws;
    _Float16* Wfrag0   = (_Float16*)(ws + 0);
    _Float16* Wfrag1   = (_Float16*)(ws + 393216);
    _Float16* Wi1frag  = (_Float16*)(ws + 786432);
    float*    hst0     = (float*)(ws + 1179648);
    float*    hst1     = (float*)(ws + 1703936);
    _Float16* houtfrag = (_Float16*)(ws + 2228224);
    _Float16* xg0t     = (_Float16*)(ws + 10616832);
    _Float16* xg1t     = (_Float16*)(ws + 35782656);

    prep_kernel<<<288, 256, 0, stream>>>(Whh0, Whh1, Wih1, Wfrag0, Wfrag1, Wi1frag);

    for (int c = 0; c <= NCH; c++) {
        if (c < NCH)
            phaseB0_kernel<<<dim3(4, 32), 256, 0, stream>>>(x, meta, Wih0, bih0, bhh0, xg0t, c);
        recur_kernel<<<64, 512, 0, stream>>>(Wfrag0, bhh0, xg0t, hst0,
                                             Wfrag1, bhh1, xg1t, hst1,
                                             houtfrag, fcW, fcb, out, c);
        if (c < NCH)
            phaseB1_kernel<<<512, 256, 0, stream>>>(houtfrag, Wi1frag, bih1, bhh1, xg1t);
    }
}